// Round 5
// baseline (1802.723 us; speedup 1.0000x reference)
//
#include <hip/hip_runtime.h>

#define N_TOK 131072
#define KCB   1024
#define D     256
#define NL    4
#define BT    64      // tokens per block (final/full kernels)
#define BTK   64      // topk tokens per block
#define BCH   64      // codes per chunk in topk
#define DELTA 3e-4f

typedef _Float16 halfx8 __attribute__((ext_vector_type(8)));
typedef _Float16 halfx4 __attribute__((ext_vector_type(4)));
typedef float    floatx16 __attribute__((ext_vector_type(16)));

// ---------- numpy pairwise_sum replication (n=256, sum of squares) ----------
__device__ __forceinline__ float np_pw128_sq(const float* a) {
  float r[8];
  #pragma unroll
  for (int j = 0; j < 8; ++j) r[j] = __fmul_rn(a[j], a[j]);
  #pragma unroll
  for (int i = 8; i < 128; i += 8)
    #pragma unroll
    for (int j = 0; j < 8; ++j) r[j] = __fadd_rn(r[j], __fmul_rn(a[i + j], a[i + j]));
  float t01 = __fadd_rn(r[0], r[1]), t23 = __fadd_rn(r[2], r[3]);
  float t45 = __fadd_rn(r[4], r[5]), t67 = __fadd_rn(r[6], r[7]);
  return __fadd_rn(__fadd_rn(t01, t23), __fadd_rn(t45, t67));
}
__device__ __forceinline__ float np_pw256_sq(const float* a) {
  return __fadd_rn(np_pw128_sq(a), np_pw128_sq(a + 128));
}

__global__ void zero_cnt(int* cnt) { if (threadIdx.x < 8) cnt[threadIdx.x] = 0; }

__global__ __launch_bounds__(256) void eh2_kernel(const float* __restrict__ cb,
                                                  float* __restrict__ eh) {
  int row = blockIdx.x * 256 + threadIdx.x;
  if (row < NL * KCB) eh[row] = np_pw256_sq(cb + (size_t)row * D);
}

__global__ __launch_bounds__(256) void cvt_cbh(const float* __restrict__ cb,
                                               _Float16* __restrict__ cbh) {
  int i = (blockIdx.x * 256 + threadIdx.x) * 4;
  float4 v = *(const float4*)(cb + i);
  halfx4 h;
  h[0] = (_Float16)v.x; h[1] = (_Float16)v.y; h[2] = (_Float16)v.z; h[3] = (_Float16)v.w;
  *(halfx4*)(cbh + i) = h;
}

// codebook transpose: cbT[l][k][code] (f32) for coalesced full-scan gathers
__global__ __launch_bounds__(256) void transpose_cb(const float* __restrict__ cb,
                                                    float* __restrict__ cbT) {
  __shared__ float ts[64][257];
  const int tid = threadIdx.x;
  const int l = blockIdx.x >> 4;
  const int c0 = (blockIdx.x & 15) * 64;
  const float* src = cb + ((size_t)l * KCB + c0) * D;
  for (int r = 0; r < 64; ++r) ts[r][tid] = src[r * D + tid];
  __syncthreads();
  float* dst = cbT + (size_t)l * (KCB * D);
  for (int kk = 0; kk < 64; ++kk) {
    int k = kk * 4 + (tid >> 6);
    int c = tid & 63;
    dst[k * KCB + c0 + c] = ts[c][k];
  }
}

__device__ __forceinline__ void gload16(const _Float16* g, _Float16* l) {
  __builtin_amdgcn_global_load_lds((const __attribute__((address_space(1))) void*)g,
                                   (__attribute__((address_space(3))) void*)l, 16, 0, 0);
}

// MFMA 32x32x16 f16 selection: (m1,i1,m2) per token over 1024 codes.
// A in registers; B via global_load_lds into single-buffered 32KB smem.
template<int LAYER>
__global__ __launch_bounds__(256, 3) void topk_mfma(
    const float* __restrict__ z, const float* __restrict__ cb,
    const _Float16* __restrict__ cbh, const float* __restrict__ eh,
    int* __restrict__ idxw, int* __restrict__ listF, int* __restrict__ cntA,
    float* __restrict__ out_idx)
{
  // smem: phase 1 = Ah[64 tok][256] swizzled; main loop = Bh[64 codes][256] swizzled;
  // epilogue = float scr[64][2][4]. 16B block b of row r lives at slot (b ^ (r&7)).
  __shared__ __align__(16) _Float16 smem[BTK * 256];   // 32 KB
  __shared__ int hist[(LAYER > 0 ? LAYER : 1)][BTK];

  const int tid = threadIdx.x;
  const int tok0 = blockIdx.x * BTK;

  if (LAYER > 0 && tid < LAYER * BTK) {
    int l = tid / BTK, t = tid - l * BTK;
    hist[l][t] = idxw[l * N_TOK + tok0 + t];
  }
  __syncthreads();

  // A build: np-exact f32 residual chain -> f16 RNE -> swizzled store (tid = d)
  #pragma unroll 4
  for (int r = 0; r < BTK; ++r) {
    float v = z[(size_t)(tok0 + r) * D + tid];
    #pragma unroll
    for (int l = 0; l < LAYER; ++l) {
      float q = cb[((size_t)l * KCB + hist[l][r]) * D + tid];
      float tmp = __fsub_rn(q, v);
      float u = __fadd_rn(v, tmp);
      v = __fsub_rn(v, u);
    }
    int b = tid >> 3, p = b ^ (r & 7);
    smem[(r * 32 + p) * 8 + (tid & 7)] = (_Float16)v;
  }
  __syncthreads();

  const int lane = tid & 63, w = tid >> 6;
  const int rg = w >> 1, cg = w & 1;

  // A fragments -> registers: wave's 32 tokens x 256 k (64 VGPR)
  const int arow = rg * 32 + (lane & 31);
  halfx8 af[16];
  #pragma unroll
  for (int ks = 0; ks < 16; ++ks) {
    int b = ks * 2 + (lane >> 5);
    int p = b ^ (arow & 7);
    af[ks] = *(const halfx8*)&smem[(arow * 32 + p) * 8];
  }
  __syncthreads();   // all waves done reading A before B overwrites smem

  const _Float16* srcL = cbh + (size_t)LAYER * KCB * D;
  // wave w stages chunk-local rows [w*16, w*16+16): 8 instrs x (2 rows = 1KB)
  auto issueB = [&](int ct) {
    #pragma unroll
    for (int j = 0; j < 8; ++j) {
      int rl = w * 16 + 2 * j + (lane >> 5);
      int b  = (lane & 31) ^ (rl & 7);          // pre-swizzled global source
      gload16(srcL + (size_t)(ct * BCH + rl) * D + b * 8,
              &smem[(w * 16 + 2 * j) * 256]);   // linear LDS dest
    }
  };

  float m1[16], m2[16]; int i1[16];
  #pragma unroll
  for (int s = 0; s < 16; ++s) { m1[s] = m2[s] = 1e30f; i1[s] = 0x7fffffff; }

  issueB(0);
  const int brow = cg * 32 + (lane & 31);
  for (int ct = 0; ct < KCB / BCH; ++ct) {
    int code = ct * BCH + cg * 32 + (lane & 31);
    float h = eh[LAYER * KCB + code];            // issued before DMA of ct+1
    __syncthreads();                             // drains vmcnt -> B(ct) ready
    floatx16 acc;
    #pragma unroll
    for (int e = 0; e < 16; ++e) acc[e] = 0.f;
    #pragma unroll
    for (int ks = 0; ks < 16; ++ks) {
      int b = ks * 2 + (lane >> 5);
      int p = b ^ (brow & 7);
      halfx8 bv = *(const halfx8*)&smem[(brow * 32 + p) * 8];
      acc = __builtin_amdgcn_mfma_f32_32x32x16_f16(af[ks], bv, acc, 0, 0, 0);
    }
    __syncthreads();                             // all waves done reading B(ct)
    if (ct + 1 < KCB / BCH) issueB(ct + 1);      // async overwrite begins
    // register-only scores overlap the DMA
    #pragma unroll
    for (int s = 0; s < 16; ++s) {
      float sc = __builtin_fmaf(acc[s], -2.f, h);
      m2[s] = fminf(m2[s], fmaxf(m1[s], sc));
      bool c = sc < m1[s];
      i1[s] = c ? code : i1[s];
      m1[s] = c ? sc : m1[s];
    }
  }

  // merge across the 32 code-lanes (masks keep bit5 -> same token rows)
  #pragma unroll
  for (int mm = 1; mm <= 16; mm <<= 1) {
    #pragma unroll
    for (int s = 0; s < 16; ++s) {
      float om1 = __shfl_xor(m1[s], mm);
      int   oi1 = __shfl_xor(i1[s], mm);
      float om2 = __shfl_xor(m2[s], mm);
      bool c1 = (om1 < m1[s]) || (om1 == m1[s] && oi1 < i1[s]);
      float lose = c1 ? m1[s] : om1;
      m2[s] = fminf(fminf(m2[s], om2), lose);
      m1[s] = c1 ? om1 : m1[s];
      i1[s] = c1 ? oi1 : i1[s];
    }
  }

  float* scr = (float*)smem;   // [64 rows][2 cg][4]
  if ((lane & 31) == 0) {
    #pragma unroll
    for (int s = 0; s < 16; ++s) {
      int row = rg * 32 + (s & 3) + 8 * (s >> 2) + 4 * (lane >> 5);
      float* pp = scr + (row * 2 + cg) * 4;
      pp[0] = m1[s]; pp[1] = __int_as_float(i1[s]); pp[2] = m2[s];
    }
  }
  __syncthreads();
  if (tid < BTK) {
    const float* pa = scr + (tid * 2 + 0) * 4;
    const float* pb = scr + (tid * 2 + 1) * 4;
    float am1 = pa[0], am2 = pa[2]; int ai1 = __float_as_int(pa[1]);
    float bm1 = pb[0], bm2 = pb[2]; int bi1 = __float_as_int(pb[1]);
    bool c1 = (bm1 < am1) || (bm1 == am1 && bi1 < ai1);
    float m1c = c1 ? bm1 : am1;
    int   i1c = c1 ? bi1 : ai1;
    float m2c = fminf(fminf(am2, bm2), c1 ? am1 : bm1);
    int tok = tok0 + tid;
    idxw[LAYER * N_TOK + tok] = i1c;
    out_idx[(size_t)LAYER * N_TOK + tok] = (float)i1c;
    if (m2c - m1c < DELTA) {
      int p = atomicAdd(&cntA[LAYER], 1);
      listF[p] = tok;
    }
  }
}

// Full np-exact 1024-code scan via transposed codebook; one block per flagged token.
template<int LAYER>
__global__ __launch_bounds__(256) void full_kernel(
    const float* __restrict__ z, const float* __restrict__ cb,
    const float* __restrict__ cbT, const float* __restrict__ eh,
    const int* __restrict__ listF, const int* __restrict__ cntA,
    int* __restrict__ idxw, float* __restrict__ out_idx)
{
  __shared__ float rs[D];
  __shared__ float rv[4]; __shared__ int ri[4];
  const int tid = threadIdx.x;
  const int w = tid >> 6, lane = tid & 63;
  const int cnt = cntA[LAYER];
  for (int j = blockIdx.x; j < cnt; j += gridDim.x) {
    const int token = listF[j];
    __syncthreads();
    {
      float v = z[(size_t)token * D + tid];
      #pragma unroll
      for (int l = 0; l < LAYER; ++l) {
        int id = idxw[l * N_TOK + token];
        float q = cb[((size_t)l * KCB + id) * D + tid];
        float tmp = __fsub_rn(q, v);
        float u = __fadd_rn(v, tmp);
        v = __fsub_rn(v, u);
      }
      rs[tid] = v;
    }
    __syncthreads();
    float acc[4] = {0.f, 0.f, 0.f, 0.f};
    const float* cT = cbT + (size_t)LAYER * (KCB * D);
    for (int k = 0; k < D; ++k) {
      float r = rs[k];
      #pragma unroll
      for (int jj = 0; jj < 4; ++jj)
        acc[jj] = __fmaf_rn(r, cT[k * KCB + jj * 256 + tid], acc[jj]);
    }
    float a = np_pw256_sq(rs);
    float bd = 1e30f; int bi = 0x7fffffff;
    #pragma unroll
    for (int jj = 0; jj < 4; ++jj) {
      int code = jj * 256 + tid;
      float t1 = __fadd_rn(a, eh[LAYER * KCB + code]);
      float dist = __fsub_rn(t1, __fmul_rn(2.0f, acc[jj]));
      if (dist < bd || (dist == bd && code < bi)) { bd = dist; bi = code; }
    }
    #pragma unroll
    for (int mm = 1; mm <= 32; mm <<= 1) {
      float od = __shfl_xor(bd, mm); int oi = __shfl_xor(bi, mm);
      if (od < bd || (od == bd && oi < bi)) { bd = od; bi = oi; }
    }
    if (lane == 0) { rv[w] = bd; ri[w] = bi; }
    __syncthreads();
    if (tid == 0) {
      float b0 = rv[0]; int i0 = ri[0];
      #pragma unroll
      for (int q = 1; q < 4; ++q)
        if (rv[q] < b0 || (rv[q] == b0 && ri[q] < i0)) { b0 = rv[q]; i0 = ri[q]; }
      idxw[LAYER * N_TOK + token] = i0;
      out_idx[(size_t)LAYER * N_TOK + token] = (float)i0;
    }
  }
}

// Full 4-layer np-f32 replay: q_sum + loss partials
__global__ __launch_bounds__(256) void final_replay(
    const float* __restrict__ z, const float* __restrict__ cb,
    const int* __restrict__ idxw, double* __restrict__ lossB,
    float* __restrict__ out_q)
{
  __shared__ int hist4[NL][BT];
  __shared__ double red[4];
  const int tid = threadIdx.x;
  const int tok0 = blockIdx.x * BT;
  { int l = tid >> 6, t = tid & 63; hist4[l][t] = idxw[l * N_TOK + tok0 + t]; }
  __syncthreads();
  double lacc = 0.0;
  for (int t = 0; t < BT; ++t) {
    float v = z[(size_t)(tok0 + t) * D + tid];
    float qs = 0.f;
    #pragma unroll
    for (int l = 0; l < NL; ++l) {
      float q = cb[((size_t)l * KCB + hist4[l][t]) * D + tid];
      float tmp = __fsub_rn(q, v);
      lacc += (double)tmp * (double)tmp;
      float u = __fadd_rn(v, tmp);
      qs = __fadd_rn(qs, u);
      v = __fsub_rn(v, u);
    }
    out_q[(size_t)(tok0 + t) * D + tid] = qs;
  }
  const int w = tid >> 6, lane = tid & 63;
  #pragma unroll
  for (int m = 32; m; m >>= 1) lacc += __shfl_xor(lacc, m);
  if (lane == 0) red[w] = lacc;
  __syncthreads();
  if (tid == 0) lossB[blockIdx.x] = red[0] + red[1] + red[2] + red[3];
}

__global__ __launch_bounds__(256) void finalize_np(const double* __restrict__ lossB,
                                                   float* __restrict__ out0) {
  __shared__ double red[4];
  double s = 0.0;
  for (int i = threadIdx.x; i < N_TOK / BT; i += 256) s += lossB[i];
  #pragma unroll
  for (int m = 32; m; m >>= 1) s += __shfl_xor(s, m);
  const int w = threadIdx.x >> 6, lane = threadIdx.x & 63;
  if (lane == 0) red[w] = s;
  __syncthreads();
  if (threadIdx.x == 0) {
    double t = red[0] + red[1] + red[2] + red[3];
    out0[0] = (float)(1.25 * t / ((double)N_TOK * (double)D));
  }
}

extern "C" void kernel_launch(void* const* d_in, const int* in_sizes, int n_in,
                              void* d_out, int out_size, void* d_ws, size_t ws_size,
                              hipStream_t stream)
{
  (void)in_sizes; (void)n_in; (void)out_size; (void)ws_size;
  const float* z  = (const float*)d_in[0];
  const float* cb = (const float*)d_in[1];
  float* out = (float*)d_out;

  // ws layout (disjoint, ~9 MB)
  float*    eh    = (float*)d_ws;                          // 16 KB
  _Float16* cbh   = (_Float16*)((char*)d_ws + 0x010000);   // 2 MB
  int*      cntA  = (int*)((char*)d_ws + 0x210000);        // 64 B  [layer]
  int*      listF = (int*)((char*)d_ws + 0x220000);        // 512 KB
  int*      idxw  = (int*)((char*)d_ws + 0x2A0000);        // 2 MB  [4][N]
  double*   lossB = (double*)((char*)d_ws + 0x4A0000);     // 16 KB
  float*    cbT   = (float*)((char*)d_ws + 0x500000);      // 4 MB  [4][256][1024]

  float* out_q   = out + 1;                      // [N, 256]
  float* out_idx = out + 1 + (size_t)N_TOK * D;  // [4, N]

  zero_cnt<<<dim3(1), dim3(64), 0, stream>>>(cntA);
  cvt_cbh<<<dim3(1024), dim3(256), 0, stream>>>(cb, cbh);
  eh2_kernel<<<dim3(16), dim3(256), 0, stream>>>(cb, eh);
  transpose_cb<<<dim3(64), dim3(256), 0, stream>>>(cb, cbT);

  topk_mfma<0><<<dim3(N_TOK / BTK), dim3(256), 0, stream>>>(z, cb, cbh, eh, idxw, listF, cntA, out_idx);
  full_kernel<0><<<dim3(2048), dim3(256), 0, stream>>>(z, cb, cbT, eh, listF, cntA, idxw, out_idx);

  topk_mfma<1><<<dim3(N_TOK / BTK), dim3(256), 0, stream>>>(z, cb, cbh, eh, idxw, listF, cntA, out_idx);
  full_kernel<1><<<dim3(2048), dim3(256), 0, stream>>>(z, cb, cbT, eh, listF, cntA, idxw, out_idx);

  topk_mfma<2><<<dim3(N_TOK / BTK), dim3(256), 0, stream>>>(z, cb, cbh, eh, idxw, listF, cntA, out_idx);
  full_kernel<2><<<dim3(2048), dim3(256), 0, stream>>>(z, cb, cbT, eh, listF, cntA, idxw, out_idx);

  topk_mfma<3><<<dim3(N_TOK / BTK), dim3(256), 0, stream>>>(z, cb, cbh, eh, idxw, listF, cntA, out_idx);
  full_kernel<3><<<dim3(2048), dim3(256), 0, stream>>>(z, cb, cbT, eh, listF, cntA, idxw, out_idx);

  final_replay<<<dim3(N_TOK / BT), dim3(256), 0, stream>>>(z, cb, idxw, lossB, out_q);
  finalize_np<<<dim3(1), dim3(256), 0, stream>>>(lossB, out);
}

// Round 6
// 1239.605 us; speedup vs baseline: 1.4543x; 1.4543x over previous
//
#include <hip/hip_runtime.h>

#define N_TOK 131072
#define KCB   1024
#define D     256
#define NL    4
#define BT    64      // tokens per batch (pair/final kernels)
#define BTK   128     // topk tokens per block (4 waves x 32)
#define BCH   64      // codes per chunk in topk
#define DELTA 3e-4f

typedef _Float16 halfx8 __attribute__((ext_vector_type(8)));
typedef _Float16 halfx4 __attribute__((ext_vector_type(4)));
typedef float    floatx16 __attribute__((ext_vector_type(16)));

// ---------- numpy pairwise_sum replication (n=256, sum of squares) ----------
__device__ __forceinline__ float np_pw128_sq(const float* a) {
  float r[8];
  #pragma unroll
  for (int j = 0; j < 8; ++j) r[j] = __fmul_rn(a[j], a[j]);
  #pragma unroll
  for (int i = 8; i < 128; i += 8)
    #pragma unroll
    for (int j = 0; j < 8; ++j) r[j] = __fadd_rn(r[j], __fmul_rn(a[i + j], a[i + j]));
  float t01 = __fadd_rn(r[0], r[1]), t23 = __fadd_rn(r[2], r[3]);
  float t45 = __fadd_rn(r[4], r[5]), t67 = __fadd_rn(r[6], r[7]);
  return __fadd_rn(__fadd_rn(t01, t23), __fadd_rn(t45, t67));
}
__device__ __forceinline__ float np_pw256_sq(const float* a) {
  return __fadd_rn(np_pw128_sq(a), np_pw128_sq(a + 128));
}

__global__ void zero_cnt(int* cnt) { if (threadIdx.x < 8) cnt[threadIdx.x] = 0; }

__global__ __launch_bounds__(256) void eh2_kernel(const float* __restrict__ cb,
                                                  float* __restrict__ eh) {
  int row = blockIdx.x * 256 + threadIdx.x;
  if (row < NL * KCB) eh[row] = np_pw256_sq(cb + (size_t)row * D);
}

__global__ __launch_bounds__(256) void cvt_cbh(const float* __restrict__ cb,
                                               _Float16* __restrict__ cbh) {
  int i = (blockIdx.x * 256 + threadIdx.x) * 4;
  float4 v = *(const float4*)(cb + i);
  halfx4 h;
  h[0] = (_Float16)v.x; h[1] = (_Float16)v.y; h[2] = (_Float16)v.z; h[3] = (_Float16)v.w;
  *(halfx4*)(cbh + i) = h;
}

// codebook transpose: cbT[l][k][code] (f32) for coalesced full-scan gathers
__global__ __launch_bounds__(256) void transpose_cb(const float* __restrict__ cb,
                                                    float* __restrict__ cbT) {
  __shared__ float ts[64][257];
  const int tid = threadIdx.x;
  const int l = blockIdx.x >> 4;
  const int c0 = (blockIdx.x & 15) * 64;
  const float* src = cb + ((size_t)l * KCB + c0) * D;
  for (int r = 0; r < 64; ++r) ts[r][tid] = src[r * D + tid];
  __syncthreads();
  float* dst = cbT + (size_t)l * (KCB * D);
  for (int kk = 0; kk < 64; ++kk) {
    int k = kk * 4 + (tid >> 6);
    int c = tid & 63;
    dst[k * KCB + c0 + c] = ts[c][k];
  }
}

__device__ __forceinline__ void gload16(const _Float16* g, _Float16* l) {
  __builtin_amdgcn_global_load_lds((const __attribute__((address_space(1))) void*)g,
                                   (__attribute__((address_space(3))) void*)l, 16, 0, 0);
}

// MFMA 32x32x16 f16, transposed tile (codes=rows, tokens=cols): each lane owns ONE
// token; tracks (m1,i1,m2,i2,m3) in 5 regs. Codes staged via global_load_lds.
template<int LAYER>
__global__ __launch_bounds__(256, 3) void topk_mfma(
    const float* __restrict__ z, const float* __restrict__ cb,
    const _Float16* __restrict__ cbh, const float* __restrict__ eh,
    int* __restrict__ idxw, int* __restrict__ ti,
    int* __restrict__ listF, int* __restrict__ listP, int* __restrict__ cntA,
    float* __restrict__ out_idx)
{
  // Bh: 64 codes x 256 k, XOR-swizzled: 16B block b of row r at slot (b ^ (r&7)).
  __shared__ __align__(16) _Float16 Bh[BCH * 256];   // 32 KB
  __shared__ float eh_s[KCB];                        // 4 KB

  const int tid = threadIdx.x;
  const int lane = tid & 63, w = tid >> 6;
  const int khalf = lane >> 5;
  const int tok0 = blockIdx.x * BTK;
  const int mytok = tok0 + w * 32 + (lane & 31);

  for (int i = tid; i < KCB; i += 256) eh_s[i] = eh[LAYER * KCB + i];

  int hist[LAYER > 0 ? LAYER : 1];
  #pragma unroll
  for (int l = 0; l < LAYER; ++l) hist[l] = idxw[l * N_TOK + mytok];

  // Residual fragments straight to registers: np-exact f32 chain, f16 RNE.
  // B-frag layout: token row = lane&31 (col of C), k = khalf*8 + e within each 16-k step.
  halfx8 rfrag[16];
  #pragma unroll
  for (int ks = 0; ks < 16; ++ks) {
    const int d0 = ks * 16 + khalf * 8;
    const float* zr = z + (size_t)mytok * D + d0;
    float v[8];
    *(float4*)&v[0] = *(const float4*)zr;
    *(float4*)&v[4] = *(const float4*)(zr + 4);
    #pragma unroll
    for (int l = 0; l < LAYER; ++l) {
      const float* er = cb + ((size_t)l * KCB + hist[l]) * D + d0;
      float q[8];
      *(float4*)&q[0] = *(const float4*)er;
      *(float4*)&q[4] = *(const float4*)(er + 4);
      #pragma unroll
      for (int e = 0; e < 8; ++e) {
        float tmp = __fsub_rn(q[e], v[e]);
        float u = __fadd_rn(v[e], tmp);
        v[e] = __fsub_rn(v[e], u);
      }
    }
    halfx8 h8;
    #pragma unroll
    for (int e = 0; e < 8; ++e) h8[e] = (_Float16)v[e];
    rfrag[ks] = h8;
  }

  const _Float16* srcL = cbh + (size_t)LAYER * KCB * D;
  // wave w stages chunk rows [w*16, w*16+16): pre-swizzled global src, linear LDS dest
  auto issueB = [&](int ct) {
    #pragma unroll
    for (int j = 0; j < 8; ++j) {
      int rl = w * 16 + 2 * j + khalf;
      int b  = (lane & 31) ^ (rl & 7);
      gload16(srcL + (size_t)(ct * BCH + rl) * D + b * 8,
              &Bh[(w * 16 + 2 * j) * 256]);
    }
  };

  float m1 = 1e30f, m2 = 1e30f, m3 = 1e30f;
  int   i1 = 0x7fffffff, i2 = 0x7fffffff;

  issueB(0);
  for (int ct = 0; ct < KCB / BCH; ++ct) {
    __syncthreads();                       // drains DMA -> B(ct) ready
    floatx16 acc0, acc1;
    #pragma unroll
    for (int e = 0; e < 16; ++e) { acc0[e] = 0.f; acc1[e] = 0.f; }
    #pragma unroll
    for (int ks = 0; ks < 16; ++ks) {
      int b = ks * 2 + khalf;
      int r0 = lane & 31;
      int r1 = 32 + (lane & 31);
      halfx8 a0 = *(const halfx8*)&Bh[(r0 * 32 + (b ^ (r0 & 7))) * 8];
      halfx8 a1 = *(const halfx8*)&Bh[(r1 * 32 + (b ^ (r1 & 7))) * 8];
      acc0 = __builtin_amdgcn_mfma_f32_32x32x16_f16(a0, rfrag[ks], acc0, 0, 0, 0);
      acc1 = __builtin_amdgcn_mfma_f32_32x32x16_f16(a1, rfrag[ks], acc1, 0, 0, 0);
    }
    __syncthreads();                       // all waves done reading B(ct)
    if (ct + 1 < KCB / BCH) issueB(ct + 1);
    // register-only scoring overlaps the DMA
    #pragma unroll
    for (int t = 0; t < 2; ++t) {
      #pragma unroll
      for (int e = 0; e < 16; ++e) {
        int code = ct * BCH + t * 32 + (e & 3) + 8 * (e >> 2) + 4 * khalf;
        float h = eh_s[code];
        float sc = __builtin_fmaf(t ? acc1[e] : acc0[e], -2.f, h);
        float m1o = m1, m2o = m2;
        bool c1 = sc < m1o, c2 = sc < m2o;
        m1 = fminf(m1o, sc);
        m2 = __builtin_amdgcn_fmed3f(m1o, m2o, sc);
        m3 = __builtin_amdgcn_fmed3f(m2o, m3, fmaxf(sc, m1o));
        i2 = c1 ? i1 : (c2 ? code : i2);
        i1 = c1 ? code : i1;
      }
    }
  }

  // merge the two k-halves (lane <-> lane+32), both lanes compute identically
  float om1 = __shfl_xor(m1, 32), om2 = __shfl_xor(m2, 32), om3 = __shfl_xor(m3, 32);
  int   oi1 = __shfl_xor(i1, 32), oi2 = __shfl_xor(i2, 32);
  bool c1 = (om1 < m1) || (om1 == m1 && oi1 < i1);
  float w1v = c1 ? om1 : m1;  int w1i = c1 ? oi1 : i1;
  float l1v = c1 ? m1 : om1;  int l1i = c1 ? i1 : oi1;
  float w2v = c1 ? om2 : m2;  int w2i = c1 ? oi2 : i2;
  float l2v = c1 ? m2 : om2;
  float w3v = c1 ? om3 : m3;
  bool c2 = (l1v < w2v) || (l1v == w2v && l1i < w2i);
  float n2v = c2 ? l1v : w2v; int n2i = c2 ? l1i : w2i;
  float n3v = c2 ? fminf(w2v, l2v) : fminf(l1v, w3v);

  if (lane < 32) {
    idxw[LAYER * N_TOK + mytok] = w1i;
    out_idx[(size_t)LAYER * N_TOK + mytok] = (float)w1i;
    if (n3v - w1v < DELTA) {
      int p = atomicAdd(&cntA[LAYER * 2 + 0], 1);
      listF[p] = mytok;
    } else if (n2v - w1v < DELTA) {
      ti[mytok * 2 + 0] = w1i;
      ti[mytok * 2 + 1] = n2i;
      int p = atomicAdd(&cntA[LAYER * 2 + 1], 1);
      listP[p] = mytok;
    }
  }
}

// np-bitwise {i1,i2} comparison for pair-flagged tokens (compacted, batched by 64)
template<int LAYER>
__global__ __launch_bounds__(256) void pair_kernel(
    const float* __restrict__ z, const float* __restrict__ cb,
    const float* __restrict__ eh, const int* __restrict__ ti,
    const int* __restrict__ listP, const int* __restrict__ cntA,
    int* __restrict__ idxw, float* __restrict__ out_idx)
{
  __shared__ float rs[BT][D + 1];
  __shared__ float a_sh[BT];
  __shared__ int toks[BT];
  const int tid = threadIdx.x;
  const int cnt = cntA[LAYER * 2 + 1];
  const int nbat = (cnt + BT - 1) / BT;
  for (int bat = blockIdx.x; bat < nbat; bat += gridDim.x) {
    const int base = bat * BT;
    const int nt = min(BT, cnt - base);
    __syncthreads();
    if (tid < BT) toks[tid] = listP[base + min(tid, nt - 1)];
    __syncthreads();
    for (int i = 0; i < BT; ++i) {
      if (i >= nt) break;
      int token = toks[i];
      float v = z[(size_t)token * D + tid];
      #pragma unroll
      for (int l = 0; l < LAYER; ++l) {
        int id = idxw[l * N_TOK + token];
        float q = cb[((size_t)l * KCB + id) * D + tid];
        float tmp = __fsub_rn(q, v);
        float u = __fadd_rn(v, tmp);
        v = __fsub_rn(v, u);
      }
      rs[i][tid] = v;
    }
    __syncthreads();
    if (tid < nt) a_sh[tid] = np_pw256_sq(&rs[tid][0]);
    __syncthreads();
    const int tl = tid >> 1, c = tid & 1;
    if (tid < 2 * nt) {
      int token = toks[tl];
      int cand = ti[token * 2 + c];
      const float* er = cb + ((size_t)LAYER * KCB + cand) * D;
      const float* rr = &rs[tl][0];
      float acc = 0.f;
      #pragma unroll 8
      for (int k = 0; k < D; ++k) acc = __fmaf_rn(rr[k], er[k], acc);
      float t1 = __fadd_rn(a_sh[tl], eh[LAYER * KCB + cand]);
      float dist = __fsub_rn(t1, __fmul_rn(2.0f, acc));
      float od = __shfl_xor(dist, 1);
      int   oi = __shfl_xor(cand, 1);
      if (c == 0) {
        int best = ((od < dist) || (od == dist && oi < cand)) ? oi : cand;
        idxw[LAYER * N_TOK + token] = best;
        out_idx[(size_t)LAYER * N_TOK + token] = (float)best;
      }
    }
  }
}

// Full np-exact 1024-code scan via transposed codebook; one block per flagged token.
template<int LAYER>
__global__ __launch_bounds__(256) void full_kernel(
    const float* __restrict__ z, const float* __restrict__ cb,
    const float* __restrict__ cbT, const float* __restrict__ eh,
    const int* __restrict__ listF, const int* __restrict__ cntA,
    int* __restrict__ idxw, float* __restrict__ out_idx)
{
  __shared__ float rs[D];
  __shared__ float rv[4]; __shared__ int ri[4];
  const int tid = threadIdx.x;
  const int w = tid >> 6, lane = tid & 63;
  const int cnt = cntA[LAYER * 2 + 0];
  for (int j = blockIdx.x; j < cnt; j += gridDim.x) {
    const int token = listF[j];
    __syncthreads();
    {
      float v = z[(size_t)token * D + tid];
      #pragma unroll
      for (int l = 0; l < LAYER; ++l) {
        int id = idxw[l * N_TOK + token];
        float q = cb[((size_t)l * KCB + id) * D + tid];
        float tmp = __fsub_rn(q, v);
        float u = __fadd_rn(v, tmp);
        v = __fsub_rn(v, u);
      }
      rs[tid] = v;
    }
    __syncthreads();
    float acc[4] = {0.f, 0.f, 0.f, 0.f};
    const float* cT = cbT + (size_t)LAYER * (KCB * D);
    for (int k = 0; k < D; ++k) {
      float r = rs[k];
      #pragma unroll
      for (int jj = 0; jj < 4; ++jj)
        acc[jj] = __fmaf_rn(r, cT[k * KCB + jj * 256 + tid], acc[jj]);
    }
    float a = np_pw256_sq(rs);
    float bd = 1e30f; int bi = 0x7fffffff;
    #pragma unroll
    for (int jj = 0; jj < 4; ++jj) {
      int code = jj * 256 + tid;
      float t1 = __fadd_rn(a, eh[LAYER * KCB + code]);
      float dist = __fsub_rn(t1, __fmul_rn(2.0f, acc[jj]));
      if (dist < bd || (dist == bd && code < bi)) { bd = dist; bi = code; }
    }
    #pragma unroll
    for (int mm = 1; mm <= 32; mm <<= 1) {
      float od = __shfl_xor(bd, mm); int oi = __shfl_xor(bi, mm);
      if (od < bd || (od == bd && oi < bi)) { bd = od; bi = oi; }
    }
    if (lane == 0) { rv[w] = bd; ri[w] = bi; }
    __syncthreads();
    if (tid == 0) {
      float b0 = rv[0]; int i0 = ri[0];
      #pragma unroll
      for (int q = 1; q < 4; ++q)
        if (rv[q] < b0 || (rv[q] == b0 && ri[q] < i0)) { b0 = rv[q]; i0 = ri[q]; }
      idxw[LAYER * N_TOK + token] = i0;
      out_idx[(size_t)LAYER * N_TOK + token] = (float)i0;
    }
  }
}

// Full 4-layer np-f32 replay: q_sum + loss partials
__global__ __launch_bounds__(256) void final_replay(
    const float* __restrict__ z, const float* __restrict__ cb,
    const int* __restrict__ idxw, double* __restrict__ lossB,
    float* __restrict__ out_q)
{
  __shared__ int hist4[NL][BT];
  __shared__ double red[4];
  const int tid = threadIdx.x;
  const int tok0 = blockIdx.x * BT;
  { int l = tid >> 6, t = tid & 63; hist4[l][t] = idxw[l * N_TOK + tok0 + t]; }
  __syncthreads();
  double lacc = 0.0;
  for (int t = 0; t < BT; ++t) {
    float v = z[(size_t)(tok0 + t) * D + tid];
    float qs = 0.f;
    #pragma unroll
    for (int l = 0; l < NL; ++l) {
      float q = cb[((size_t)l * KCB + hist4[l][t]) * D + tid];
      float tmp = __fsub_rn(q, v);
      lacc += (double)tmp * (double)tmp;
      float u = __fadd_rn(v, tmp);
      qs = __fadd_rn(qs, u);
      v = __fsub_rn(v, u);
    }
    out_q[(size_t)(tok0 + t) * D + tid] = qs;
  }
  const int w = tid >> 6, lane = tid & 63;
  #pragma unroll
  for (int m = 32; m; m >>= 1) lacc += __shfl_xor(lacc, m);
  if (lane == 0) red[w] = lacc;
  __syncthreads();
  if (tid == 0) lossB[blockIdx.x] = red[0] + red[1] + red[2] + red[3];
}

__global__ __launch_bounds__(256) void finalize_np(const double* __restrict__ lossB,
                                                   float* __restrict__ out0) {
  __shared__ double red[4];
  double s = 0.0;
  for (int i = threadIdx.x; i < N_TOK / BT; i += 256) s += lossB[i];
  #pragma unroll
  for (int m = 32; m; m >>= 1) s += __shfl_xor(s, m);
  const int w = threadIdx.x >> 6, lane = threadIdx.x & 63;
  if (lane == 0) red[w] = s;
  __syncthreads();
  if (threadIdx.x == 0) {
    double t = red[0] + red[1] + red[2] + red[3];
    out0[0] = (float)(1.25 * t / ((double)N_TOK * (double)D));
  }
}

extern "C" void kernel_launch(void* const* d_in, const int* in_sizes, int n_in,
                              void* d_out, int out_size, void* d_ws, size_t ws_size,
                              hipStream_t stream)
{
  (void)in_sizes; (void)n_in; (void)out_size; (void)ws_size;
  const float* z  = (const float*)d_in[0];
  const float* cb = (const float*)d_in[1];
  float* out = (float*)d_out;

  // ws layout (disjoint, ~11 MB)
  float*    eh    = (float*)d_ws;                          // 16 KB
  _Float16* cbh   = (_Float16*)((char*)d_ws + 0x010000);   // 2 MB
  int*      cntA  = (int*)((char*)d_ws + 0x210000);        // 32 B [layer][full,pair]
  int*      listF = (int*)((char*)d_ws + 0x220000);        // 512 KB
  int*      listP = (int*)((char*)d_ws + 0x2A0000);        // 512 KB
  int*      ti    = (int*)((char*)d_ws + 0x320000);        // 1 MB  [N][2]
  int*      idxw  = (int*)((char*)d_ws + 0x420000);        // 2 MB  [4][N]
  double*   lossB = (double*)((char*)d_ws + 0x620000);     // 16 KB
  float*    cbT   = (float*)((char*)d_ws + 0x700000);      // 4 MB  [4][256][1024]

  float* out_q   = out + 1;                      // [N, 256]
  float* out_idx = out + 1 + (size_t)N_TOK * D;  // [4, N]

  zero_cnt<<<dim3(1), dim3(64), 0, stream>>>(cntA);
  cvt_cbh<<<dim3(1024), dim3(256), 0, stream>>>(cb, cbh);
  eh2_kernel<<<dim3(16), dim3(256), 0, stream>>>(cb, eh);
  transpose_cb<<<dim3(64), dim3(256), 0, stream>>>(cb, cbT);

  topk_mfma<0><<<dim3(N_TOK / BTK), dim3(256), 0, stream>>>(z, cb, cbh, eh, idxw, ti, listF, listP, cntA, out_idx);
  pair_kernel<0><<<dim3(256), dim3(256), 0, stream>>>(z, cb, eh, ti, listP, cntA, idxw, out_idx);
  full_kernel<0><<<dim3(1024), dim3(256), 0, stream>>>(z, cb, cbT, eh, listF, cntA, idxw, out_idx);

  topk_mfma<1><<<dim3(N_TOK / BTK), dim3(256), 0, stream>>>(z, cb, cbh, eh, idxw, ti, listF, listP, cntA, out_idx);
  pair_kernel<1><<<dim3(256), dim3(256), 0, stream>>>(z, cb, eh, ti, listP, cntA, idxw, out_idx);
  full_kernel<1><<<dim3(1024), dim3(256), 0, stream>>>(z, cb, cbT, eh, listF, cntA, idxw, out_idx);

  topk_mfma<2><<<dim3(N_TOK / BTK), dim3(256), 0, stream>>>(z, cb, cbh, eh, idxw, ti, listF, listP, cntA, out_idx);
  pair_kernel<2><<<dim3(256), dim3(256), 0, stream>>>(z, cb, eh, ti, listP, cntA, idxw, out_idx);
  full_kernel<2><<<dim3(1024), dim3(256), 0, stream>>>(z, cb, cbT, eh, listF, cntA, idxw, out_idx);

  topk_mfma<3><<<dim3(N_TOK / BTK), dim3(256), 0, stream>>>(z, cb, cbh, eh, idxw, ti, listF, listP, cntA, out_idx);
  pair_kernel<3><<<dim3(256), dim3(256), 0, stream>>>(z, cb, eh, ti, listP, cntA, idxw, out_idx);
  full_kernel<3><<<dim3(1024), dim3(256), 0, stream>>>(z, cb, cbT, eh, listF, cntA, idxw, out_idx);

  final_replay<<<dim3(N_TOK / BT), dim3(256), 0, stream>>>(z, cb, idxw, lossB, out_q);
  finalize_np<<<dim3(1), dim3(256), 0, stream>>>(lossB, out);
}